// Round 7
// baseline (172.447 us; speedup 1.0000x reference)
//
#include <hip/hip_runtime.h>

// Replicate XLA:CPU's exact f32 rounding: no mul+add fusion anywhere
// (hipcc default is -ffp-contract=fast; XLA:CPU emits separate fmul/fadd
// with xla_cpu_enable_fast_math=false).
//
// Perf notes from rounds 3-6 (MI355X, gfx950):
//  - Packed f32 (v_pk_*_f32) is RATE-NEUTRAL for wave64 on CDNA4 (r6: forced
//    asm pk = 92.2us vs scalar 90.2us; VOP3P constant pairs cost VGPRs/movs).
//    Scalar f32 with VOP2 literal constants is the best encoding here.
//  - Kernel is VALU-issue-bound: ~430 threefry-ARX + ~400 Cephes-log slots
//    per element, all mandated bit-exact. HBM ~12%, MfmaUtil 0.
#pragma clang fp contract(off)

#define TPB 256

// ---------------------------------------------------------------------------
// Threefry-2x32, key = (0, 42). Partitionable counting: element j <- block
// (x0 = hi = 0, x1 = lo = j); 32-bit draw = bits1 ^ bits2. (Verified r2-r6.)
// Scalar int ARX; full avalanche -> no cross-draw sharing possible.
// ---------------------------------------------------------------------------
__device__ __forceinline__ uint32_t rotl32(uint32_t x, uint32_t n) {
  return (x << n) | (x >> (32u - n));
}

__device__ __forceinline__ uint32_t threefry_draw32(uint32_t j) {
  const uint32_t ks1 = 42u;
  const uint32_t ks2 = 0x1BD11BDAu ^ 42u;  // 0x1BD11BF0
  uint32_t x0 = 0u;        // counts_hi = 0 (+ ks0 = 0)
  uint32_t x1 = j + ks1;   // counts_lo + ks1

#define TFR(r) { x0 += x1; x1 = rotl32(x1, r); x1 ^= x0; }
  TFR(13u) TFR(15u) TFR(26u) TFR(6u)   x0 += ks1; x1 += ks2 + 1u;
  TFR(17u) TFR(29u) TFR(16u) TFR(24u)  x0 += ks2; x1 += 0u  + 2u;
  TFR(13u) TFR(15u) TFR(26u) TFR(6u)   x0 += 0u;  x1 += ks1 + 3u;
  TFR(17u) TFR(29u) TFR(16u) TFR(24u)  x0 += ks1; x1 += ks2 + 4u;
  TFR(13u) TFR(15u) TFR(26u) TFR(6u)   x0 += ks2; x1 += 0u  + 5u;
#undef TFR
  return x0 ^ x1;
}

// ---------------------------------------------------------------------------
// Cephes/Eigen plog core (XLA:CPU GenerateVF32Log), separate mul/add,
// SIGN-AGNOSTIC: takes the raw bit pattern, computes log(|x|) — mantissa and
// bfe-extracted exponent fields are identical for x and -x, so the caller
// gets log(-x) for negative x at zero cost. Valid for |x| positive normal.
// (Chain verified bit-exact r2-r6.)
// ---------------------------------------------------------------------------
__device__ __forceinline__ float xla_log_core(uint32_t bits) {
  float m = __uint_as_float((bits & 0x007fffffu) | 0x3f000000u);  // [0.5, 1)
  bool mask = m < 0.707106781186547524f;
  float e = (float)((int)((bits >> 23) & 0xffu) - (mask ? 127 : 126));  // exact
  float tmp = mask ? m : 0.0f;
  m = m - 1.0f;
  m = m + tmp;

  float x2 = m * m;
  float x3 = x2 * m;

  float y  =  7.0376836292e-2f * m + -1.1514610310e-1f;
  float y1 = -1.2420140846e-1f * m +  1.4249322787e-1f;
  float y2 =  2.0000714765e-1f * m + -2.4999993993e-1f;
  y  = y  * m +  1.1676998740e-1f;
  y1 = y1 * m + -1.6668057665e-1f;
  y2 = y2 * m +  3.3333331174e-1f;
  y  = y * x3 + y1;
  y  = y * x3 + y2;
  y  = y * x3;

  float t1 = -2.12194440e-4f * e;   // q1 * e
  float t2 = 0.5f * x2;
  y = y + t1;
  m = m - t2;
  float t3 = 0.693359375f * e;      // q2 * e
  m = m + y;
  m = m + t3;
  return m;
}

__device__ __forceinline__ float xla_logf(float x) {
  return xla_log_core(__float_as_uint(x));
}

// Cephes pexp replica (setup kernel only; verified r2).
__device__ __forceinline__ float xla_expf(float xin) {
  float xc = fminf(xin, 88.3762626647950f);
  xc = fmaxf(xc, -88.3762626647949f);
  float fx = floorf(xc * 1.44269504088896341f + 0.5f);
  float tmp = 0.693359375f * fx;
  float z   = -2.12194440e-4f * fx;
  float x = xc - tmp;
  x = x - z;
  z = x * x;
  float y = x * 1.9875691500e-4f + 1.3981999507e-3f;
  y = y * x + 8.3334519073e-3f;
  y = y * x + 4.1665795894e-2f;
  y = y * x + 1.6666665459e-1f;
  y = y * x + 5.0000001201e-1f;
  y = y * z + x;
  y = y + 1.0f;
  int n = (int)fx;
  float p2n = __uint_as_float((uint32_t)(n + 0x7f) << 23);
  return fmaxf(y * p2n, xin);
}

// l2 = log(-log(u)) from one raw draw, bit-exact to the reference chain:
//   f = bitcast((bits>>9)|1.0f) - 1;  u = (f==0 ? tiny : f) == max(f, tiny)
//   (f in {0} U [2^-23,1), no NaN => IEEE max == the select exactly);
//   l1 = log(u) < 0 strictly  =>  log(-l1) via the sign-agnostic core.
// Caller forms s = lp - l2 == gumbel + logits (add commutative, neg exact).
__device__ __forceinline__ float log_neg_log_u(uint32_t r) {
  float f = __uint_as_float((r >> 9) | 0x3f800000u) - 1.0f;  // [0, 1)
  float u = fmaxf(f, 1.17549435082228750797e-38f);           // tiny
  float l1 = xla_log_core(__float_as_uint(u));
  return xla_log_core(__float_as_uint(l1));                  // log(-l1)
}

// ---------------------------------------------------------------------------
// Setup: logp = log_softmax(W.T + b), same Cephes rounding as reference.
// ---------------------------------------------------------------------------
__global__ void setup_logp(const float* __restrict__ W,
                           const float* __restrict__ bvec,
                           float* __restrict__ logp) {
  if (threadIdx.x == 0 && blockIdx.x == 0) {
    for (int c = 0; c < 2; ++c) {
      float x0 = W[0 * 2 + c] + bvec[0];
      float x1 = W[1 * 2 + c] + bvec[1];
      float x2 = W[2 * 2 + c] + bvec[2];
      float mx = fmaxf(fmaxf(fmaxf(-__builtin_inff(), x0), x1), x2);
      float s0 = x0 - mx, s1 = x1 - mx, s2 = x2 - mx;
      float e0 = xla_expf(s0);
      float e1 = xla_expf(s1);
      float e2 = xla_expf(s2);
      float se = (e0 + e1) + e2;
      float lse = xla_logf(se);
      logp[c * 3 + 0] = s0 - lse;
      logp[c * 3 + 1] = s1 - lse;
      logp[c * 3 + 2] = s2 - lse;
    }
  }
}

// Per-element result bundle.
struct ElemOut {
  float u0, w0, w1, l0, l1;
};

// Full pipeline for batch element b: 6 draws at base=6b -> 6 gumbel sums ->
// per-card argmax (strict >, first max wins = XLA tie rule) -> outputs.
__device__ __forceinline__ ElemOut process_element(uint32_t b, int card,
                                                   const float lp[6]) {
  uint32_t base = b * 6u;

  // s[k] = lp[k] - log(-log(u_k)); 6 independent chains (good ILP).
  float s0 = lp[0] - log_neg_log_u(threefry_draw32(base + 0u));
  float s1 = lp[1] - log_neg_log_u(threefry_draw32(base + 1u));
  float s2 = lp[2] - log_neg_log_u(threefry_draw32(base + 2u));
  float s3 = lp[3] - log_neg_log_u(threefry_draw32(base + 3u));
  float s4 = lp[4] - log_neg_log_u(threefry_draw32(base + 4u));
  float s5 = lp[5] - log_neg_log_u(threefry_draw32(base + 5u));

  int a0 = 0; float best0 = s0;
  if (s1 > best0) { best0 = s1; a0 = 1; }
  if (s2 > best0) { best0 = s2; a0 = 2; }
  int a1 = 0; float best1 = s3;
  if (s4 > best1) { best1 = s4; a1 = 1; }
  if (s5 > best1) { best1 = s5; a1 = 2; }

  ElemOut o;
  // Explicit selects (no dynamic array index -> no scratch risk).
  o.l0 = (a0 == 0) ? lp[0] : ((a0 == 1) ? lp[1] : lp[2]);
  o.l1 = (a1 == 0) ? lp[3] : ((a1 == 1) ? lp[4] : lp[5]);
  // beliefs: a0==a1 -> (.5,.5); else (1,0) if card==0 else (0,1).
  bool eq = (a0 == a1);
  bool c0 = (card == 0);
  o.u0 = (float)(c0 ? a0 : a1);
  o.w0 = eq ? 0.5f : (c0 ? 1.0f : 0.0f);
  o.w1 = eq ? 0.5f : (c0 ? 0.0f : 1.0f);
  return o;
}

// ---------------------------------------------------------------------------
// Main: TWO batch elements per thread (b = 2t, 2t+1) — measured-best mapping
// (r4: 90.2us vs 92.9 @1elem, 90.7 @4elem). int2 cards load; float2/float4
// stores. Requires B even (BATCH = 4194304).
// Output (f32, concat): u0[B] | beliefs[B][2] | log_cf[B][2].
// ---------------------------------------------------------------------------
__global__ void __launch_bounds__(TPB) sample_kernel2(
    const int* __restrict__ cards, const float* __restrict__ lp_g,
    float* __restrict__ out_u0, float* __restrict__ out_beliefs,
    float* __restrict__ out_logcf, int npairs) {
  int t = blockIdx.x * TPB + threadIdx.x;
  if (t >= npairs) return;

  float lp[6];
#pragma unroll
  for (int i = 0; i < 6; ++i) lp[i] = lp_g[i];

  int2 c2 = reinterpret_cast<const int2*>(cards)[t];

  ElemOut e0 = process_element((uint32_t)(2 * t),      c2.x, lp);
  ElemOut e1 = process_element((uint32_t)(2 * t) + 1u, c2.y, lp);

  reinterpret_cast<float2*>(out_u0)[t]      = make_float2(e0.u0, e1.u0);
  reinterpret_cast<float4*>(out_beliefs)[t] = make_float4(e0.w0, e0.w1, e1.w0, e1.w1);
  reinterpret_cast<float4*>(out_logcf)[t]   = make_float4(e0.l0, e0.l1, e1.l0, e1.l1);
}

extern "C" void kernel_launch(void* const* d_in, const int* in_sizes, int n_in,
                              void* d_out, int out_size, void* d_ws, size_t ws_size,
                              hipStream_t stream) {
  (void)n_in; (void)out_size; (void)ws_size;
  const int* cards = (const int*)d_in[0];   // (B,) int32
  const float* W   = (const float*)d_in[1]; // (3,2) f32 row-major
  const float* bv  = (const float*)d_in[2]; // (3,)  f32
  float* out = (float*)d_out;               // u0[B] | beliefs[B*2] | log_cf[B*2]
  float* lp  = (float*)d_ws;                // 6 floats scratch

  int B = in_sizes[0];
  int npairs = B >> 1;  // BATCH = 4194304 (even)
  setup_logp<<<1, 64, 0, stream>>>(W, bv, lp);
  sample_kernel2<<<(npairs + TPB - 1) / TPB, TPB, 0, stream>>>(
      cards, lp, out, out + (size_t)B, out + (size_t)3 * B, npairs);
}

// Round 8
// 165.046 us; speedup vs baseline: 1.0448x; 1.0448x over previous
//
#include <hip/hip_runtime.h>

// Replicate XLA:CPU's exact f32 rounding: no mul+add fusion anywhere
// (hipcc default is -ffp-contract=fast; XLA:CPU emits separate fmul/fadd
// with xla_cpu_enable_fast_math=false). Applies to packed ops too (blocks
// v_pk_fma formation).
//
// Perf map (MI355X, measured r2-r7):
//   r2 scalar 1elem + LDS bcast: 100.4us | r3 f32x2 1elem: 92.9
//   r4 f32x2 2elem:              90.2    | r5 f32x2 4elem+trims: 90.7
//   r6 forced pk asm 4elem:      92.2    | r7 scalar 2elem+trims: 98.7
// Conclusion: compiler-vectorized f32x2 (VOP3P packed) cuts ~17% of issue
// slots vs scalar (busy-time 77.6 vs 93.8us); forced asm loses the gain to
// constant-pair movs; 2 elem/thread is the best mapping. VALU-issue-bound:
// HBM ~12%, MfmaUtil 0. Threefry ARX is scalar-int (no packed u32 ops).
#pragma clang fp contract(off)

#define TPB 256

typedef float f32x2 __attribute__((ext_vector_type(2)));

// ---------------------------------------------------------------------------
// Threefry-2x32, key = (0, 42). Partitionable counting: element j <- block
// (x0 = hi = 0, x1 = lo = j); 32-bit draw = bits1 ^ bits2. (Verified r2-r7.)
// ---------------------------------------------------------------------------
__device__ __forceinline__ uint32_t rotl32(uint32_t x, uint32_t n) {
  return (x << n) | (x >> (32u - n));
}

__device__ __forceinline__ uint32_t threefry_draw32(uint32_t j) {
  const uint32_t ks1 = 42u;
  const uint32_t ks2 = 0x1BD11BDAu ^ 42u;  // 0x1BD11BF0
  uint32_t x0 = 0u;        // counts_hi = 0 (+ ks0 = 0)
  uint32_t x1 = j + ks1;   // counts_lo + ks1

#define TFR(r) { x0 += x1; x1 = rotl32(x1, r); x1 ^= x0; }
  TFR(13u) TFR(15u) TFR(26u) TFR(6u)   x0 += ks1; x1 += ks2 + 1u;
  TFR(17u) TFR(29u) TFR(16u) TFR(24u)  x0 += ks2; x1 += 0u  + 2u;
  TFR(13u) TFR(15u) TFR(26u) TFR(6u)   x0 += 0u;  x1 += ks1 + 3u;
  TFR(17u) TFR(29u) TFR(16u) TFR(24u)  x0 += ks1; x1 += ks2 + 4u;
  TFR(13u) TFR(15u) TFR(26u) TFR(6u)   x0 += ks2; x1 += 0u  + 5u;
#undef TFR
  return x0 ^ x1;
}

// ---------------------------------------------------------------------------
// Scalar Cephes/Eigen plog + pexp replicas (XLA:CPU GenerateVF32Log/Exp),
// separate mul/add. Used only by the tiny setup kernel. (Verified r2.)
// ---------------------------------------------------------------------------
__device__ __forceinline__ float xla_logf(float xin) {
  uint32_t bits = __float_as_uint(xin);
  int emm0 = (int)(bits >> 23) - 0x7f;
  float m = __uint_as_float((bits & 0x007fffffu) | 0x3f000000u);
  float e = (float)emm0 + 1.0f;
  bool mask = m < 0.707106781186547524f;
  float tmp = mask ? m : 0.0f;
  m = m - 1.0f;
  e = e - (mask ? 1.0f : 0.0f);
  m = m + tmp;
  float x2 = m * m;
  float x3 = x2 * m;
  float y  =  7.0376836292e-2f * m + -1.1514610310e-1f;
  float y1 = -1.2420140846e-1f * m +  1.4249322787e-1f;
  float y2 =  2.0000714765e-1f * m + -2.4999993993e-1f;
  y  = y  * m +  1.1676998740e-1f;
  y1 = y1 * m + -1.6668057665e-1f;
  y2 = y2 * m +  3.3333331174e-1f;
  y  = y * x3 + y1;
  y  = y * x3 + y2;
  y  = y * x3;
  float t1 = -2.12194440e-4f * e;
  float t2 = 0.5f * x2;
  y = y + t1;
  m = m - t2;
  float t3 = 0.693359375f * e;
  m = m + y;
  m = m + t3;
  return m;
}

__device__ __forceinline__ float xla_expf(float xin) {
  float xc = fminf(xin, 88.3762626647950f);
  xc = fmaxf(xc, -88.3762626647949f);
  float fx = floorf(xc * 1.44269504088896341f + 0.5f);
  float tmp = 0.693359375f * fx;
  float z   = -2.12194440e-4f * fx;
  float x = xc - tmp;
  x = x - z;
  z = x * x;
  float y = x * 1.9875691500e-4f + 1.3981999507e-3f;
  y = y * x + 8.3334519073e-3f;
  y = y * x + 4.1665795894e-2f;
  y = y * x + 1.6666665459e-1f;
  y = y * x + 5.0000001201e-1f;
  y = y * z + x;
  y = y + 1.0f;
  int n = (int)fx;
  float p2n = __uint_as_float((uint32_t)(n + 0x7f) << 23);
  return fmaxf(y * p2n, xin);
}

// ---------------------------------------------------------------------------
// Packed (2-wide) Cephes plog core, SIGN-AGNOSTIC: takes raw bit patterns,
// computes log(|x|) — mantissa and bfe-extracted exponent fields are
// identical for x and -x, so callers pass a negative value's bits to get
// log(-x) free. Written on f32x2 so the compiler vectorizes the float chain
// to VOP3P packed ops (measured: -17% issue slots vs scalar, r4 vs r7);
// per-half rounding is bit-identical IEEE, verified absmax=0 r3-r6.
// Int glue (mantissa splice, exponent, selects) stays scalar.
// ---------------------------------------------------------------------------
__device__ __forceinline__ f32x2 xla_logf_pk_core(uint32_t b0, uint32_t b1) {
  f32x2 m;
  m.x = __uint_as_float((b0 & 0x007fffffu) | 0x3f000000u);  // [0.5, 1)
  m.y = __uint_as_float((b1 & 0x007fffffu) | 0x3f000000u);
  bool mk0 = m.x < 0.707106781186547524f;
  bool mk1 = m.y < 0.707106781186547524f;
  f32x2 e;
  e.x = (float)((int)((b0 >> 23) & 0xffu) - (mk0 ? 127 : 126));  // exact cvt
  e.y = (float)((int)((b1 >> 23) & 0xffu) - (mk1 ? 127 : 126));
  f32x2 tmp;
  tmp.x = mk0 ? m.x : 0.0f;
  tmp.y = mk1 ? m.y : 0.0f;
  m = m - 1.0f;
  m = m + tmp;

  f32x2 x2 = m * m;
  f32x2 x3 = x2 * m;

  f32x2 y  = m * 7.0376836292e-2f  + -1.1514610310e-1f;
  f32x2 y1 = m * -1.2420140846e-1f +  1.4249322787e-1f;
  f32x2 y2 = m * 2.0000714765e-1f  + -2.4999993993e-1f;
  y  = y  * m +  1.1676998740e-1f;
  y1 = y1 * m + -1.6668057665e-1f;
  y2 = y2 * m +  3.3333331174e-1f;
  y  = y * x3 + y1;
  y  = y * x3 + y2;
  y  = y * x3;

  f32x2 t1 = e * -2.12194440e-4f;
  f32x2 t2 = x2 * 0.5f;
  y = y + t1;
  m = m - t2;
  f32x2 t3 = e * 0.693359375f;
  m = m + y;
  m = m + t3;
  return m;
}

// l2 = log(-log(u)) for two raw draws, bit-exact to the reference chain:
//   f = bitcast((bits>>9)|1.0f) - 1;  u = (f==0 ? tiny : f) == max(f, tiny)
//   (f in {0} U [2^-23,1), no NaN => IEEE max == the select exactly);
//   l1 = log(u) < 0 strictly (u < 1)  =>  log(-l1) via sign-agnostic core.
__device__ __forceinline__ f32x2 log_neg_log_u(uint32_t r0, uint32_t r1) {
  f32x2 f;
  f.x = __uint_as_float((r0 >> 9) | 0x3f800000u);
  f.y = __uint_as_float((r1 >> 9) | 0x3f800000u);
  f = f - 1.0f;                                        // [0, 1)
  float ux = fmaxf(f.x, 1.17549435082228750797e-38f);  // tiny
  float uy = fmaxf(f.y, 1.17549435082228750797e-38f);
  f32x2 l1 = xla_logf_pk_core(__float_as_uint(ux), __float_as_uint(uy));
  return xla_logf_pk_core(__float_as_uint(l1.x), __float_as_uint(l1.y));
}

// ---------------------------------------------------------------------------
// Setup: logp = log_softmax(W.T + b), same Cephes rounding as reference.
// ---------------------------------------------------------------------------
__global__ void setup_logp(const float* __restrict__ W,
                           const float* __restrict__ bvec,
                           float* __restrict__ logp) {
  if (threadIdx.x == 0 && blockIdx.x == 0) {
    for (int c = 0; c < 2; ++c) {
      float x0 = W[0 * 2 + c] + bvec[0];
      float x1 = W[1 * 2 + c] + bvec[1];
      float x2 = W[2 * 2 + c] + bvec[2];
      float mx = fmaxf(fmaxf(fmaxf(-__builtin_inff(), x0), x1), x2);
      float s0 = x0 - mx, s1 = x1 - mx, s2 = x2 - mx;
      float e0 = xla_expf(s0);
      float e1 = xla_expf(s1);
      float e2 = xla_expf(s2);
      float se = (e0 + e1) + e2;
      float lse = xla_logf(se);
      logp[c * 3 + 0] = s0 - lse;
      logp[c * 3 + 1] = s1 - lse;
      logp[c * 3 + 2] = s2 - lse;
    }
  }
}

// Per-element result bundle.
struct ElemOut {
  float u0, w0, w1, l0, l1;
};

// Full pipeline for batch element b: 6 draws at base=6b -> 3 packed gumbel
// pairs (card0 action k packed with card1 action k) -> per-card argmax
// (strict >, first max wins = XLA tie rule) -> outputs.
__device__ __forceinline__ ElemOut process_element(uint32_t b, int card,
                                                   const float lp[6]) {
  uint32_t base = b * 6u;
  uint32_t r[6];
#pragma unroll
  for (int k = 0; k < 6; ++k) r[k] = threefry_draw32(base + (uint32_t)k);

  f32x2 s[3];
#pragma unroll
  for (int k = 0; k < 3; ++k) {
    f32x2 l2 = log_neg_log_u(r[k], r[k + 3]);
    f32x2 lpk;
    lpk.x = lp[k];
    lpk.y = lp[3 + k];
    s[k] = lpk - l2;   // == gumbel + logits (add commutative, negation exact)
  }

  int a0 = 0; float best0 = s[0].x;
  if (s[1].x > best0) { best0 = s[1].x; a0 = 1; }
  if (s[2].x > best0) { best0 = s[2].x; a0 = 2; }
  int a1 = 0; float best1 = s[0].y;
  if (s[1].y > best1) { best1 = s[1].y; a1 = 1; }
  if (s[2].y > best1) { best1 = s[2].y; a1 = 2; }

  ElemOut o;
  // Explicit selects (no dynamic array index -> no scratch risk).
  o.l0 = (a0 == 0) ? lp[0] : ((a0 == 1) ? lp[1] : lp[2]);
  o.l1 = (a1 == 0) ? lp[3] : ((a1 == 1) ? lp[4] : lp[5]);
  // beliefs: a0==a1 -> (.5,.5); else (1,0) if card==0 else (0,1).
  bool eq = (a0 == a1);
  bool c0 = (card == 0);
  o.u0 = (float)(c0 ? a0 : a1);
  o.w0 = eq ? 0.5f : (c0 ? 1.0f : 0.0f);
  o.w1 = eq ? 0.5f : (c0 ? 0.0f : 1.0f);
  return o;
}

// ---------------------------------------------------------------------------
// Main: TWO batch elements per thread (b = 2t, 2t+1) — measured-best mapping.
// int2 cards load; float2/float4 stores. Requires B even (BATCH = 4194304).
// Output (f32, concat): u0[B] | beliefs[B][2] | log_cf[B][2].
// ---------------------------------------------------------------------------
__global__ void __launch_bounds__(TPB) sample_kernel2(
    const int* __restrict__ cards, const float* __restrict__ lp_g,
    float* __restrict__ out_u0, float* __restrict__ out_beliefs,
    float* __restrict__ out_logcf, int npairs) {
  int t = blockIdx.x * TPB + threadIdx.x;
  if (t >= npairs) return;

  float lp[6];
#pragma unroll
  for (int i = 0; i < 6; ++i) lp[i] = lp_g[i];

  int2 c2 = reinterpret_cast<const int2*>(cards)[t];

  ElemOut e0 = process_element((uint32_t)(2 * t),      c2.x, lp);
  ElemOut e1 = process_element((uint32_t)(2 * t) + 1u, c2.y, lp);

  reinterpret_cast<float2*>(out_u0)[t]      = make_float2(e0.u0, e1.u0);
  reinterpret_cast<float4*>(out_beliefs)[t] = make_float4(e0.w0, e0.w1, e1.w0, e1.w1);
  reinterpret_cast<float4*>(out_logcf)[t]   = make_float4(e0.l0, e0.l1, e1.l0, e1.l1);
}

extern "C" void kernel_launch(void* const* d_in, const int* in_sizes, int n_in,
                              void* d_out, int out_size, void* d_ws, size_t ws_size,
                              hipStream_t stream) {
  (void)n_in; (void)out_size; (void)ws_size;
  const int* cards = (const int*)d_in[0];   // (B,) int32
  const float* W   = (const float*)d_in[1]; // (3,2) f32 row-major
  const float* bv  = (const float*)d_in[2]; // (3,)  f32
  float* out = (float*)d_out;               // u0[B] | beliefs[B*2] | log_cf[B*2]
  float* lp  = (float*)d_ws;                // 6 floats scratch

  int B = in_sizes[0];
  int npairs = B >> 1;  // BATCH = 4194304 (even)
  setup_logp<<<1, 64, 0, stream>>>(W, bv, lp);
  sample_kernel2<<<(npairs + TPB - 1) / TPB, TPB, 0, stream>>>(
      cards, lp, out, out + (size_t)B, out + (size_t)3 * B, npairs);
}